// Round 15
// baseline (116.571 us; speedup 1.0000x reference)
//
#include <hip/hip_runtime.h>
#include <hip/hip_bf16.h>

constexpr int B_  = 8;
constexpr int S_  = 512;
constexpr int V_  = 30522;
constexpr int V2_ = V_ / 2;                      // 15261 float2 per row
constexpr int V4_ = V_ / 4;                      // 7630 full float4 per row (+1 float2 tail)

typedef float f32x4 __attribute__((ext_vector_type(4)));

// ---------------- Kernel 1: masked partial max-pool, balanced row slices ----------
// (R11 version — proven best; all cache-policy variants were neutral.)
constexpr int K1_THREADS = 1024;
constexpr int VSPLIT  = 4;
constexpr int SLICE4  = 1908;                    // float4 per slice (slice 3: 1906 + tail)
constexpr int NSCHUNK = 16;                      // slices -> (4,16,8)=512 blocks
constexpr int NSLOT   = 2;                       // 2 float4 per thread (2048 >= 1908)

__global__ __launch_bounds__(K1_THREADS)
void splade_partial_max(const float* __restrict__ logits,
                        const int* __restrict__ mask,
                        float* __restrict__ partial)     // [NSCHUNK][B][V_] in ws
{
    __shared__ int s_idx[S_];
    __shared__ int s_cnt;
    const int vs = blockIdx.x;
    const int sc = blockIdx.y;
    const int b  = blockIdx.z;

    // Wave 0 compacts ALL active rows of batch b via ballot prefix (no atomics).
    if (threadIdx.x < 64) {
        const int lane = threadIdx.x;
        int cnt = 0;
        for (int base = 0; base < S_; base += 64) {
            const int m = mask[b * S_ + base + lane] != 0;
            const unsigned long long bal = __ballot(m);
            if (m) s_idx[cnt + (int)__popcll(bal & ((1ull << lane) - 1ull))] = base + lane;
            cnt += (int)__popcll(bal);
        }
        if (lane == 0) s_cnt = cnt;
    }
    __syncthreads();
    const int n = s_cnt;

    // Balanced slice of the compacted row list (consecutive in memory).
    const int r_lo = (sc * n) / NSCHUNK;
    const int r_hi = ((sc + 1) * n) / NSCHUNK;

    const int len4 = (vs == VSPLIT - 1) ? (V4_ - vs * SLICE4) : SLICE4;  // 1908 / 1906
    int  col4[NSLOT];
    bool valid[NSLOT];
#pragma unroll
    for (int p = 0; p < NSLOT; ++p) {
        const int idx4 = threadIdx.x + p * K1_THREADS;
        valid[p] = (idx4 < len4);
        col4[p]  = valid[p] ? (vs * SLICE4 + idx4) : 0;
    }

    f32x4 acc[NSLOT];
#pragma unroll
    for (int p = 0; p < NSLOT; ++p) acc[p] = (f32x4)(0.f);   // relu clamp folded in

    const bool do_tail = (vs == VSPLIT - 1) && (threadIdx.x == 0);
    float tail0 = 0.f, tail1 = 0.f;

    int r = r_lo;
    for (; r + 1 < r_hi; r += 2) {                           // 2-row pipeline
        const int sa = s_idx[r], sb = s_idx[r + 1];
        const float* ra = logits + (size_t)(b * S_ + sa) * V_;
        const float* rb = logits + (size_t)(b * S_ + sb) * V_;
        f32x4 xa[NSLOT], xb[NSLOT];
#pragma unroll
        for (int p = 0; p < NSLOT; ++p)
            xa[p] = *reinterpret_cast<const f32x4*>(ra + 4 * col4[p]);
#pragma unroll
        for (int p = 0; p < NSLOT; ++p)
            xb[p] = *reinterpret_cast<const f32x4*>(rb + 4 * col4[p]);
        if (do_tail) {
            const float2 t0 = *reinterpret_cast<const float2*>(ra + 2 * (V2_ - 1));
            const float2 t1 = *reinterpret_cast<const float2*>(rb + 2 * (V2_ - 1));
            tail0 = fmaxf(tail0, fmaxf(t0.x, t1.x));
            tail1 = fmaxf(tail1, fmaxf(t0.y, t1.y));
        }
#pragma unroll
        for (int p = 0; p < NSLOT; ++p) {
#pragma unroll
            for (int q = 0; q < 4; ++q)
                acc[p][q] = fmaxf(acc[p][q], fmaxf(xa[p][q], xb[p][q]));
        }
    }
    if (r < r_hi) {                                          // odd tail row
        const float* ra = logits + (size_t)(b * S_ + s_idx[r]) * V_;
        f32x4 xa[NSLOT];
#pragma unroll
        for (int p = 0; p < NSLOT; ++p)
            xa[p] = *reinterpret_cast<const f32x4*>(ra + 4 * col4[p]);
        if (do_tail) {
            const float2 t0 = *reinterpret_cast<const float2*>(ra + 2 * (V2_ - 1));
            tail0 = fmaxf(tail0, t0.x);
            tail1 = fmaxf(tail1, t0.y);
        }
#pragma unroll
        for (int p = 0; p < NSLOT; ++p) {
#pragma unroll
            for (int q = 0; q < 4; ++q)
                acc[p][q] = fmaxf(acc[p][q], xa[p][q]);
        }
    }

    float* dst = partial + ((size_t)sc * B_ + b) * V_;
#pragma unroll
    for (int p = 0; p < NSLOT; ++p)
        if (valid[p])
            *reinterpret_cast<f32x4*>(dst + 4 * col4[p]) = acc[p];
    if (do_tail) {
        dst[2 * (V2_ - 1)]     = tail0;
        dst[2 * (V2_ - 1) + 1] = tail1;
    }
}

// ---------------- Kernel M: WIDE merge of NSCHUNK partials -> out ----------------
constexpr int KM_THREADS  = 256;
constexpr int KM_BLOCKS_X = (V2_ + KM_THREADS - 1) / KM_THREADS;   // 60

__global__ __launch_bounds__(KM_THREADS)
void splade_merge(const float* __restrict__ partial, float* __restrict__ out)
{
    const int b    = blockIdx.y;
    const int idx2 = blockIdx.x * KM_THREADS + threadIdx.x;
    if (idx2 >= V2_) return;
    const float2* p0 = reinterpret_cast<const float2*>(partial) + (size_t)b * V2_ + idx2;
    float2 m = make_float2(0.0f, 0.0f);
#pragma unroll
    for (int gg = 0; gg < NSCHUNK; ++gg) {
        const float2 x = p0[(size_t)gg * B_ * V2_];
        m.x = fmaxf(m.x, x.x);
        m.y = fmaxf(m.y, x.y);
    }
    reinterpret_cast<float2*>(out)[(size_t)b * V2_ + idx2] = m;
}

// ---------------- Kernel 2: per-row exact top-k threshold, QUATERNARY search ------
// Same exact semantics as the proven binary version (k-th largest with ties,
// = top_values[...,-1]), but 3 midpoints per barrier step: range shrinks 4x per
// step -> ~16 barriers instead of 31. Ballots are cheap (VALU); the 16-wave
// barrier was the per-step cost.
constexpr int K2_BLOCK = 1024;
constexpr int NPT2 = (V2_ + K2_BLOCK - 1) / K2_BLOCK;    // 15 pairs -> 30 uints
constexpr int MAXIT = 18;                                // 16 quaternary + binary tail

__global__ __launch_bounds__(K2_BLOCK)
void splade_topk_kernel(float* __restrict__ out,
                        const int* __restrict__ topk_ptr)
{
    const int b = blockIdx.x;
    const int k = topk_ptr[0];
    float2* row2 = reinterpret_cast<float2*>(out) + (size_t)b * V2_;

    unsigned int v[2 * NPT2];            // register cache, static indexing only
#pragma unroll
    for (int i = 0; i < NPT2; ++i) {
        const int idx2 = threadIdx.x + i * K2_BLOCK;
        float2 x = make_float2(0.0f, 0.0f);              // OOB zeros never counted
        if (idx2 < V2_) x = row2[idx2];
        v[2 * i]     = __float_as_uint(x.x);
        v[2 * i + 1] = __float_as_uint(x.y);
    }

    __shared__ int s_cnt[MAXIT * 3];
    for (int i = threadIdx.x; i < MAXIT * 3; i += K2_BLOCK) s_cnt[i] = 0;
    __syncthreads();

    // invariant: count(bits >= lo) >= k,  count(bits >= hi) < k
    unsigned int lo = 0u, hi = 0x7f800000u;
    for (int it = 0; it < MAXIT; ++it) {
        const unsigned int range = hi - lo;
        if (range <= 1u) break;                          // uniform across block
        const unsigned int d = range >> 2;
        unsigned int m1, m2, m3;
        if (d == 0u) {                                   // range 2..3: binary tail
            m1 = m2 = m3 = lo + (range >> 1);            // mid >= lo+1
        } else {
            m1 = lo + d; m2 = lo + 2 * d; m3 = lo + 3 * d;   // lo < m1 < m2 < m3 < hi
        }
        int c1 = 0, c2 = 0, c3 = 0;
#pragma unroll
        for (int i = 0; i < 2 * NPT2; ++i) {             // wave-uniform counts
            c1 += (int)__popcll(__ballot(v[i] >= m1));
            c2 += (int)__popcll(__ballot(v[i] >= m2));
            c3 += (int)__popcll(__ballot(v[i] >= m3));
        }
        if ((threadIdx.x & 63) == 0) {
            atomicAdd(&s_cnt[it * 3 + 0], c1);
            atomicAdd(&s_cnt[it * 3 + 1], c2);
            atomicAdd(&s_cnt[it * 3 + 2], c3);
        }
        __syncthreads();                                 // the ONLY barrier per step
        const int n1 = s_cnt[it * 3 + 0];
        const int n2 = s_cnt[it * 3 + 1];
        const int n3 = s_cnt[it * 3 + 2];
        if      (n3 >= k) { lo = m3;          }
        else if (n2 >= k) { lo = m2; hi = m3; }
        else if (n1 >= k) { lo = m1; hi = m2; }
        else              { hi = m1;          }
    }

    const unsigned int T = lo;           // exactly the k-th largest value's bits
#pragma unroll
    for (int i = 0; i < NPT2; ++i) {
        const int idx2 = threadIdx.x + i * K2_BLOCK;
        if (idx2 < V2_) {
            const unsigned int a = v[2 * i], c = v[2 * i + 1];
            float rx = 0.0f, ry = 0.0f;
            if (a >= T) rx = log1pf(__uint_as_float(a));
            if (c >= T) ry = log1pf(__uint_as_float(c));
            row2[idx2] = make_float2(rx, ry);
        }
    }
}

extern "C" void kernel_launch(void* const* d_in, const int* in_sizes, int n_in,
                              void* d_out, int out_size, void* d_ws, size_t ws_size,
                              hipStream_t stream) {
    const float* logits = (const float*)d_in[0];
    const int*   mask   = (const int*)d_in[1];
    const int*   topk   = (const int*)d_in[2];
    float*       out    = (float*)d_out;
    float*       ws     = (float*)d_ws;   // needs NSCHUNK*B*V*4 = 15.6 MB of scratch

    dim3 g1(VSPLIT, NSCHUNK, B_);
    splade_partial_max<<<g1, K1_THREADS, 0, stream>>>(logits, mask, ws);
    dim3 gm(KM_BLOCKS_X, B_);
    splade_merge<<<gm, KM_THREADS, 0, stream>>>(ws, out);
    splade_topk_kernel<<<B_, K2_BLOCK, 0, stream>>>(out, topk);
}

// Round 16
// 81.703 us; speedup vs baseline: 1.4268x; 1.4268x over previous
//
#include <hip/hip_runtime.h>
#include <hip/hip_bf16.h>

constexpr int B_  = 8;
constexpr int S_  = 512;
constexpr int V_  = 30522;
constexpr int V2_ = V_ / 2;                      // 15261 float2 per row
constexpr int V4_ = V_ / 4;                      // 7630 full float4 per row (+1 float2 tail)

typedef float f32x4 __attribute__((ext_vector_type(4)));

// ---------------- Kernel 1: masked partial max-pool, CHUNKED row streaming --------
// (Exact R10 configuration — best measured: 81.7 us.)
// Block (vs, sc, b) streams contiguous ~30.5 KB float4 slices of the active rows of
// S-chunk sc (rows memory-consecutive modulo mask gaps), partial max in registers.
constexpr int K1_THREADS = 1024;
constexpr int VSPLIT  = 4;
constexpr int SLICE4  = 1908;                    // float4 per slice (slice 3: 1906 + tail)
constexpr int NSCHUNK = 16;                      // S-chunks -> (4,16,8)=512 blocks=2/CU
constexpr int SCHUNK  = S_ / NSCHUNK;            // 32 rows per chunk (single ballot)
constexpr int NSLOT   = 2;                       // 2 float4 per thread (2048 >= 1908)

__global__ __launch_bounds__(K1_THREADS)
void splade_partial_max(const float* __restrict__ logits,
                        const int* __restrict__ mask,
                        float* __restrict__ partial)     // [NSCHUNK][B][V_] in ws
{
    __shared__ int s_idx[SCHUNK];
    __shared__ int s_cnt;
    const int vs = blockIdx.x;
    const int sc = blockIdx.y;
    const int b  = blockIdx.z;
    const int s0 = sc * SCHUNK;

    // Wave 0 compacts the chunk's active rows in ONE ballot (SCHUNK=32 <= 64 lanes).
    if (threadIdx.x < 64) {
        const int lane = threadIdx.x;
        const int m = (lane < SCHUNK) ? (mask[b * S_ + s0 + lane] != 0) : 0;
        const unsigned long long bal = __ballot(m);
        if (m) s_idx[(int)__popcll(bal & ((1ull << lane) - 1ull))] = lane;
        if (lane == 0) s_cnt = (int)__popcll(bal);
    }
    __syncthreads();
    const int n = s_cnt;

    // Per-slot float4 column index. Invalid slots clamp to col 0 (broadcast line).
    const int len4 = (vs == VSPLIT - 1) ? (V4_ - vs * SLICE4) : SLICE4;  // 1908 / 1906
    int  col4[NSLOT];
    bool valid[NSLOT];
#pragma unroll
    for (int p = 0; p < NSLOT; ++p) {
        const int idx4 = threadIdx.x + p * K1_THREADS;
        valid[p] = (idx4 < len4);
        col4[p]  = valid[p] ? (vs * SLICE4 + idx4) : 0;
    }

    f32x4 acc[NSLOT];
#pragma unroll
    for (int p = 0; p < NSLOT; ++p) acc[p] = (f32x4)(0.f);   // relu clamp folded in

    // One thread in the last slice owns the per-row trailing float2 (V % 4 == 2).
    const bool do_tail = (vs == VSPLIT - 1) && (threadIdx.x == 0);
    float tail0 = 0.f, tail1 = 0.f;

    int r = 0;
    for (; r + 1 < n; r += 2) {                              // 2-row pipeline
        const int s0i = s_idx[r], s1i = s_idx[r + 1];
        const float* r0 = logits + (size_t)(b * S_ + s0 + s0i) * V_;
        const float* r1 = logits + (size_t)(b * S_ + s0 + s1i) * V_;
        f32x4 x0[NSLOT], x1[NSLOT];
#pragma unroll
        for (int p = 0; p < NSLOT; ++p)
            x0[p] = *reinterpret_cast<const f32x4*>(r0 + 4 * col4[p]);
#pragma unroll
        for (int p = 0; p < NSLOT; ++p)
            x1[p] = *reinterpret_cast<const f32x4*>(r1 + 4 * col4[p]);
        if (do_tail) {
            const float2 t0 = *reinterpret_cast<const float2*>(r0 + 2 * (V2_ - 1));
            const float2 t1 = *reinterpret_cast<const float2*>(r1 + 2 * (V2_ - 1));
            tail0 = fmaxf(tail0, fmaxf(t0.x, t1.x));
            tail1 = fmaxf(tail1, fmaxf(t0.y, t1.y));
        }
#pragma unroll
        for (int p = 0; p < NSLOT; ++p) {
#pragma unroll
            for (int q = 0; q < 4; ++q)
                acc[p][q] = fmaxf(acc[p][q], fmaxf(x0[p][q], x1[p][q]));
        }
    }
    if (r < n) {                                             // odd tail row
        const float* r0 = logits + (size_t)(b * S_ + s0 + s_idx[r]) * V_;
        f32x4 x0[NSLOT];
#pragma unroll
        for (int p = 0; p < NSLOT; ++p)
            x0[p] = *reinterpret_cast<const f32x4*>(r0 + 4 * col4[p]);
        if (do_tail) {
            const float2 t0 = *reinterpret_cast<const float2*>(r0 + 2 * (V2_ - 1));
            tail0 = fmaxf(tail0, t0.x);
            tail1 = fmaxf(tail1, t0.y);
        }
#pragma unroll
        for (int p = 0; p < NSLOT; ++p) {
#pragma unroll
            for (int q = 0; q < 4; ++q)
                acc[p][q] = fmaxf(acc[p][q], x0[p][q]);
        }
    }

    float* dst = partial + ((size_t)sc * B_ + b) * V_;
#pragma unroll
    for (int p = 0; p < NSLOT; ++p)
        if (valid[p])
            *reinterpret_cast<f32x4*>(dst + 4 * col4[p]) = acc[p];
    if (do_tail) {
        dst[2 * (V2_ - 1)]     = tail0;
        dst[2 * (V2_ - 1) + 1] = tail1;
    }
}

// ---------------- Kernel M: WIDE merge of NSCHUNK partials -> out ----------------
// 480 blocks; k2 must never read the 15.6 MB of partials (8-CU bandwidth trap).
constexpr int KM_THREADS  = 256;
constexpr int KM_BLOCKS_X = (V2_ + KM_THREADS - 1) / KM_THREADS;   // 60

__global__ __launch_bounds__(KM_THREADS)
void splade_merge(const float* __restrict__ partial, float* __restrict__ out)
{
    const int b    = blockIdx.y;
    const int idx2 = blockIdx.x * KM_THREADS + threadIdx.x;
    if (idx2 >= V2_) return;
    const float2* p0 = reinterpret_cast<const float2*>(partial) + (size_t)b * V2_ + idx2;
    float2 m = make_float2(0.0f, 0.0f);
#pragma unroll
    for (int gg = 0; gg < NSCHUNK; ++gg) {
        const float2 x = p0[(size_t)gg * B_ * V2_];
        m.x = fmaxf(m.x, x.x);
        m.y = fmaxf(m.y, x.y);
    }
    reinterpret_cast<float2*>(out)[(size_t)b * V2_ + idx2] = m;
}

// ---------------- Kernel 2: per-row exact top-k threshold + finalize ----------------
// One 1024-thread block per batch row; reads ONLY the final 1 MB (8B loads).
// k-th largest (ties counted, = top_values[...,-1]) via BINARY search on the uint
// bit pattern; ballot+popc counts, one barrier per step. (Proven since round 5;
// quaternary variant regressed 3x-VALU-per-step, round 15.)
constexpr int K2_BLOCK = 1024;
constexpr int NPT2 = (V2_ + K2_BLOCK - 1) / K2_BLOCK;    // 15 pairs -> 30 uints

__global__ __launch_bounds__(K2_BLOCK)
void splade_topk_kernel(float* __restrict__ out,
                        const int* __restrict__ topk_ptr)
{
    const int b = blockIdx.x;
    const int k = topk_ptr[0];
    float2* row2 = reinterpret_cast<float2*>(out) + (size_t)b * V2_;

    unsigned int v[2 * NPT2];            // register cache, static indexing only
#pragma unroll
    for (int i = 0; i < NPT2; ++i) {
        const int idx2 = threadIdx.x + i * K2_BLOCK;
        float2 x = make_float2(0.0f, 0.0f);              // OOB zeros never counted
        if (idx2 < V2_) x = row2[idx2];
        v[2 * i]     = __float_as_uint(x.x);
        v[2 * i + 1] = __float_as_uint(x.y);
    }

    __shared__ int s_cnt[32];
    for (int i = threadIdx.x; i < 32; i += K2_BLOCK) s_cnt[i] = 0;
    __syncthreads();

    // invariant: count(bits >= lo) >= k,  count(bits >= hi) < k
    unsigned int lo = 0u, hi = 0x7f800000u;
    for (int it = 0; it < 32; ++it) {
        if (hi - lo <= 1u) break;                        // uniform across block
        const unsigned int mid = lo + ((hi - lo) >> 1);  // mid >= 1
        int c = 0;
#pragma unroll
        for (int i = 0; i < 2 * NPT2; ++i)
            c += (int)__popcll(__ballot(v[i] >= mid));   // wave-uniform count
        if ((threadIdx.x & 63) == 0) atomicAdd(&s_cnt[it], c);
        __syncthreads();                                 // the ONLY barrier per step
        const int cnt = s_cnt[it];
        if (cnt >= k) lo = mid; else hi = mid;
    }

    const unsigned int T = lo;           // exactly the k-th largest value's bits
#pragma unroll
    for (int i = 0; i < NPT2; ++i) {
        const int idx2 = threadIdx.x + i * K2_BLOCK;
        if (idx2 < V2_) {
            const unsigned int a = v[2 * i], c = v[2 * i + 1];
            float rx = 0.0f, ry = 0.0f;
            if (a >= T) rx = log1pf(__uint_as_float(a));
            if (c >= T) ry = log1pf(__uint_as_float(c));
            row2[idx2] = make_float2(rx, ry);
        }
    }
}

extern "C" void kernel_launch(void* const* d_in, const int* in_sizes, int n_in,
                              void* d_out, int out_size, void* d_ws, size_t ws_size,
                              hipStream_t stream) {
    const float* logits = (const float*)d_in[0];
    const int*   mask   = (const int*)d_in[1];
    const int*   topk   = (const int*)d_in[2];
    float*       out    = (float*)d_out;
    float*       ws     = (float*)d_ws;   // needs NSCHUNK*B*V*4 = 15.6 MB of scratch

    dim3 g1(VSPLIT, NSCHUNK, B_);
    splade_partial_max<<<g1, K1_THREADS, 0, stream>>>(logits, mask, ws);
    dim3 gm(KM_BLOCKS_X, B_);
    splade_merge<<<gm, KM_THREADS, 0, stream>>>(ws, out);
    splade_topk_kernel<<<B_, K2_BLOCK, 0, stream>>>(out, topk);
}